// Round 2
// baseline (325.888 us; speedup 1.0000x reference)
//
#include <hip/hip_runtime.h>
#include <hip/hip_bf16.h>

// ---------- types ----------
typedef __attribute__((ext_vector_type(8))) short short8;   // 8 x bf16 (4 VGPRs)
typedef __attribute__((ext_vector_type(4))) float f32x4;    // MFMA accumulator

typedef unsigned short u16;

__device__ __forceinline__ u16 f32_to_bf16(float f) {
    unsigned int u = __float_as_uint(f);
    u += 0x7fffu + ((u >> 16) & 1u);   // round-to-nearest-even
    return (u16)(u >> 16);
}

// ---------- cast fp32 -> bf16, 4 elems/thread ----------
__global__ void cast_f32_bf16_x4(const float* __restrict__ in,
                                 u16* __restrict__ out, int n4) {
    int i = blockIdx.x * blockDim.x + threadIdx.x;
    if (i >= n4) return;
    float4 v = ((const float4*)in)[i];
    ushort4 o;
    o.x = f32_to_bf16(v.x); o.y = f32_to_bf16(v.y);
    o.z = f32_to_bf16(v.z); o.w = f32_to_bf16(v.w);
    ((ushort4*)out)[i] = o;
}

// ---------- output store helpers ----------
__device__ __forceinline__ void store_c(float* p, float v) { *p = v; }
__device__ __forceinline__ void store_c(u16* p, float v)   { *p = f32_to_bf16(v); }

// ---------- GEMM: C[M,N] = A[M,K] * Bt[N,K]^T  (both row-major, contiguous K) ----------
// 128x128 block tile, BK=64, 256 threads (4 waves in 2x2), each wave 64x64 via
// 4x4 grid of v_mfma_f32_16x16x32_bf16. LDS rows padded 64->72 bf16 (2-way bank
// aliasing only, which is free on gfx950).
#define LDSS 72

template <typename OutT>
__global__ __launch_bounds__(256) void gemm_bt(
    const u16* __restrict__ Abase, const u16* __restrict__ Bbase,
    OutT* __restrict__ Cbase, int M, int N, int K,
    int lda, int ldb, int ldc,
    long long sAb, long long sBb, long long sCb)
{
    const u16* A  = Abase + (long long)blockIdx.z * sAb;
    const u16* Bt = Bbase + (long long)blockIdx.z * sBb;
    OutT*      C  = Cbase + (long long)blockIdx.z * sCb;

    __shared__ u16 sA[128 * LDSS];
    __shared__ u16 sB[128 * LDSS];

    const int t    = threadIdx.x;
    const int lane = t & 63;
    const int wave = t >> 6;
    const int wm = (wave >> 1) * 64;
    const int wn = (wave & 1) * 64;
    const int lr = lane & 15;            // fragment row (A) / col (B)
    const int lk = (lane >> 4) * 8;      // fragment k offset
    const int row0 = blockIdx.y * 128;
    const int col0 = blockIdx.x * 128;

    f32x4 acc[4][4];
#pragma unroll
    for (int i = 0; i < 4; ++i)
#pragma unroll
        for (int j = 0; j < 4; ++j)
            acc[i][j] = (f32x4){0.f, 0.f, 0.f, 0.f};

    // Tile staging: 128 rows x 64 bf16 = 1024 16B-chunks per matrix.
    // 256 threads x 4 chunks each. idx = c*256 + t -> for fixed c,
    // consecutive lanes hit consecutive 16B chunks (fully coalesced).
    for (int k0 = 0; k0 < K; k0 += 64) {
        __syncthreads();
#pragma unroll
        for (int c = 0; c < 4; ++c) {
            int idx = c * 256 + t;
            int r   = idx >> 3;          // 8 chunks per row
            int c8  = (idx & 7) * 8;     // k-offset within row (elements)
            *(uint4*)(&sA[r * LDSS + c8]) =
                *(const uint4*)(A + (long long)(row0 + r) * lda + k0 + c8);
            *(uint4*)(&sB[r * LDSS + c8]) =
                *(const uint4*)(Bt + (long long)(col0 + r) * ldb + k0 + c8);
        }
        __syncthreads();

#pragma unroll
        for (int kk = 0; kk < 64; kk += 32) {
            short8 af[4], bf[4];
#pragma unroll
            for (int i = 0; i < 4; ++i)
                af[i] = *(const short8*)(&sA[(wm + i * 16 + lr) * LDSS + kk + lk]);
#pragma unroll
            for (int i = 0; i < 4; ++i)
                bf[i] = *(const short8*)(&sB[(wn + i * 16 + lr) * LDSS + kk + lk]);
#pragma unroll
            for (int i = 0; i < 4; ++i)
#pragma unroll
                for (int j = 0; j < 4; ++j)
                    acc[i][j] = __builtin_amdgcn_mfma_f32_16x16x32_bf16(
                        af[i], bf[j], acc[i][j], 0, 0, 0);
        }
    }

    // C/D layout: col = lane&15, row = (lane>>4)*4 + reg   [m89/m91-verified]
    const int cr = (lane >> 4) * 4;
    const int cc = lane & 15;
#pragma unroll
    for (int i = 0; i < 4; ++i)
#pragma unroll
        for (int j = 0; j < 4; ++j)
#pragma unroll
            for (int r = 0; r < 4; ++r) {
                int grow = row0 + wm + i * 16 + cr + r;
                int gcol = col0 + wn + j * 16 + cc;
                store_c(&C[(long long)grow * ldc + gcol], acc[i][j][r]);
            }
}

// ---------- softmax over rows of S (fp32, len 2048) -> P (bf16) ----------
__global__ __launch_bounds__(256) void softmax_rows(
    const float* __restrict__ S, u16* __restrict__ P, float scale)
{
    const long long row = blockIdx.x;
    const float* s = S + row * 2048;
    u16* p = P + row * 2048;
    const int t = threadIdx.x;
    const int lane = t & 63, w = t >> 6;

    float v[8];
    float m = -1e30f;
#pragma unroll
    for (int i = 0; i < 8; ++i) {
        v[i] = s[t + i * 256] * scale;
        m = fmaxf(m, v[i]);
    }
#pragma unroll
    for (int off = 32; off > 0; off >>= 1) m = fmaxf(m, __shfl_xor(m, off, 64));
    __shared__ float sm[4], ss[4];
    if (lane == 0) sm[w] = m;
    __syncthreads();
    m = fmaxf(fmaxf(sm[0], sm[1]), fmaxf(sm[2], sm[3]));

    float sum = 0.f;
#pragma unroll
    for (int i = 0; i < 8; ++i) {
        v[i] = __expf(v[i] - m);
        sum += v[i];
    }
#pragma unroll
    for (int off = 32; off > 0; off >>= 1) sum += __shfl_xor(sum, off, 64);
    if (lane == 0) ss[w] = sum;
    __syncthreads();
    const float inv = 1.0f / (ss[0] + ss[1] + ss[2] + ss[3]);
#pragma unroll
    for (int i = 0; i < 8; ++i) p[t + i * 256] = f32_to_bf16(v[i] * inv);
}

// ---------- transpose V slice of qkv -> VT[b][d][s] ----------
__global__ void transpose_v(const u16* __restrict__ qkv, u16* __restrict__ VT)
{
    __shared__ u16 tile[32][33];
    const int b  = blockIdx.z;
    const int d0 = blockIdx.x * 32;
    const int s0 = blockIdx.y * 32;
    const int tx = threadIdx.x, ty = threadIdx.y;
#pragma unroll
    for (int i = 0; i < 4; ++i) {
        int s = s0 + ty + i * 8;
        tile[ty + i * 8][tx] =
            qkv[((long long)(b * 2048 + s)) * 3072 + 2048 + d0 + tx];
    }
    __syncthreads();
#pragma unroll
    for (int i = 0; i < 4; ++i) {
        int d = d0 + ty + i * 8;
        VT[((long long)(b * 1024 + d)) * 2048 + s0 + tx] = tile[tx][ty + i * 8];
    }
}

// ---------- launch ----------
extern "C" void kernel_launch(void* const* d_in, const int* in_sizes, int n_in,
                              void* d_out, int out_size, void* d_ws, size_t ws_size,
                              hipStream_t stream) {
    const float* x = (const float*)d_in[0];   // [4,2048,1024]
    const float* W = (const float*)d_in[1];   // [3072,1024]
    float* out = (float*)d_out;               // [4,2048,1024]

    char* ws = (char*)d_ws;
    // layout (bytes): Xb 16M | Wb 6M | QKV 48M | VT 16M | P 32M | S 16M  (~134 MB)
    u16*   Xb  = (u16*)(ws);
    u16*   Wb  = (u16*)(ws + 16777216LL);
    u16*   QKV = (u16*)(ws + 23068672LL);
    u16*   VT  = (u16*)(ws + 73400320LL);
    u16*   P   = (u16*)(ws + 90177536LL);
    float* S   = (float*)(ws + 123731968LL);

    // 1) casts
    cast_f32_bf16_x4<<<8192, 256, 0, stream>>>(x, Xb, 8192 * 1024 / 4);
    cast_f32_bf16_x4<<<3072, 256, 0, stream>>>(W, Wb, 3072 * 1024 / 4);

    // 2) QKV = X * W^T   [8192,3072] bf16
    gemm_bt<u16><<<dim3(24, 64, 1), 256, 0, stream>>>(
        Xb, Wb, QKV, 8192, 3072, 1024, 1024, 1024, 3072, 0, 0, 0);

    // 3) V transpose (all batches)
    transpose_v<<<dim3(32, 64, 4), dim3(32, 8), 0, stream>>>(QKV, VT);

    // 4) per batch: S = Q K^T (fp32), softmax -> P (bf16)
    for (int b = 0; b < 4; ++b) {
        const u16* Qb = QKV + (long long)b * 2048 * 3072;
        const u16* Kb = Qb + 1024;
        gemm_bt<float><<<dim3(16, 16, 1), 256, 0, stream>>>(
            Qb, Kb, S, 2048, 2048, 1024, 3072, 3072, 2048, 0, 0, 0);
        softmax_rows<<<2048, 256, 0, stream>>>(S, P + (long long)b * 2048 * 2048,
                                               0.03125f);
    }

    // 5) Y = P * V  (via VT as Bt), batched over z
    gemm_bt<float><<<dim3(8, 16, 4), 256, 0, stream>>>(
        P, VT, out, 2048, 1024, 2048, 2048, 2048, 1024,
        2048LL * 2048, 1024LL * 2048, 2048LL * 1024);
}

// Round 3
// 283.619 us; speedup vs baseline: 1.1490x; 1.1490x over previous
//
#include <hip/hip_runtime.h>
#include <hip/hip_bf16.h>

// ---------- types ----------
typedef __attribute__((ext_vector_type(8))) short short8;   // 8 x bf16 (4 VGPRs)
typedef __attribute__((ext_vector_type(4))) float f32x4;    // MFMA accumulator

typedef unsigned short u16;

__device__ __forceinline__ u16 f32_to_bf16(float f) {
    unsigned int u = __float_as_uint(f);
    u += 0x7fffu + ((u >> 16) & 1u);   // round-to-nearest-even
    return (u16)(u >> 16);
}

// async global->LDS, 16B per lane; LDS dest = wave-uniform base + lane*16
__device__ __forceinline__ void gload16(const u16* g, u16* lds_base) {
    __builtin_amdgcn_global_load_lds(
        (const __attribute__((address_space(1))) void*)g,
        (__attribute__((address_space(3))) void*)lds_base, 16, 0, 0);
}

// ---------- cast fp32 -> bf16, 4 elems/thread ----------
__global__ void cast_f32_bf16_x4(const float* __restrict__ in,
                                 u16* __restrict__ out, int n4) {
    int i = blockIdx.x * blockDim.x + threadIdx.x;
    if (i >= n4) return;
    float4 v = ((const float4*)in)[i];
    ushort4 o;
    o.x = f32_to_bf16(v.x); o.y = f32_to_bf16(v.y);
    o.z = f32_to_bf16(v.z); o.w = f32_to_bf16(v.w);
    ((ushort4*)out)[i] = o;
}

// ---------- output store helpers ----------
__device__ __forceinline__ void store_c(float* p, float v) { *p = v; }
__device__ __forceinline__ void store_c(u16* p, float v)   { *p = f32_to_bf16(v); }

// ---------- GEMM: C[M,N] = A[M,K] * Bt[N,K]^T  (both row-major, contiguous K) ----
// 128x128 block tile, BK=64, 256 threads (4 waves 2x2), each wave 64x64 via 4x4
// of v_mfma_f32_16x16x32_bf16. Staging via global_load_lds width=16 (m97
// structure). LDS unpadded (required by global_load_lds lane mapping); bank
// conflicts broken by XOR chunk swizzle: row r, 16B chunk slot p holds global
// chunk p ^ (r&7). Fragment reads are exactly one 16B chunk -> swizzle is free.

template <typename OutT>
__global__ __launch_bounds__(256) void gemm_bt(
    const u16* __restrict__ Abase, const u16* __restrict__ Bbase,
    OutT* __restrict__ Cbase, int M, int N, int K,
    int lda, int ldb, int ldc,
    long long sAb, long long sBb, long long sCb)
{
    const u16* A  = Abase + (long long)blockIdx.z * sAb;
    const u16* Bt = Bbase + (long long)blockIdx.z * sBb;
    OutT*      C  = Cbase + (long long)blockIdx.z * sCb;

    __shared__ u16 sA[128 * 64];
    __shared__ u16 sB[128 * 64];

    const int t    = threadIdx.x;
    const int lane = t & 63;
    const int wave = t >> 6;
    const int wm = (wave >> 1) * 64;
    const int wn = (wave & 1) * 64;
    const int lr = lane & 15;            // fragment row (A) / col (B)
    const int row0 = blockIdx.y * 128;
    const int col0 = blockIdx.x * 128;

    f32x4 acc[4][4];
#pragma unroll
    for (int i = 0; i < 4; ++i)
#pragma unroll
        for (int j = 0; j < 4; ++j)
            acc[i][j] = (f32x4){0.f, 0.f, 0.f, 0.f};

    // Staging: per K-tile each matrix is 128 rows x 64 bf16 (8 chunks of 16B).
    // One wave-issue covers 8 rows (64 lanes x 16B). 4 issues/wave/matrix.
    // lane -> row = base + lane/8, slot = lane&7; global chunk = slot ^ (r&7).
    const int srow = lane >> 3;                    // 0..7 within 8-row group
    const int gc   = (lane & 7) ^ srow;            // swizzled global chunk
    for (int k0 = 0; k0 < K; k0 += 64) {
        __syncthreads();
#pragma unroll
        for (int c = 0; c < 4; ++c) {
            const int rb = c * 32 + wave * 8;      // wave-uniform row base
            const int r  = rb + srow;
            gload16(A  + (long long)(row0 + r) * lda + k0 + gc * 8, &sA[rb * 64]);
            gload16(Bt + (long long)(col0 + r) * ldb + k0 + gc * 8, &sB[rb * 64]);
        }
        __syncthreads();   // compiler emits s_waitcnt vmcnt(0) before s_barrier

#pragma unroll
        for (int kk = 0; kk < 64; kk += 32) {
            const int cb = (lane >> 4) + (kk >> 3);   // chunk index 0..7
            const int sl = (cb ^ (lr & 7)) * 8;       // swizzled slot offset (elems)
            short8 af[4], bf[4];
#pragma unroll
            for (int i = 0; i < 4; ++i) {
                af[i] = *(const short8*)(&sA[(wm + i * 16 + lr) * 64 + sl]);
                bf[i] = *(const short8*)(&sB[(wn + i * 16 + lr) * 64 + sl]);
            }
#pragma unroll
            for (int i = 0; i < 4; ++i)
#pragma unroll
                for (int j = 0; j < 4; ++j)
                    acc[i][j] = __builtin_amdgcn_mfma_f32_16x16x32_bf16(
                        af[i], bf[j], acc[i][j], 0, 0, 0);
        }
    }

    // C/D layout: col = lane&15, row = (lane>>4)*4 + reg   [m89/m91-verified]
    const int cr = (lane >> 4) * 4;
    const int cc = lane & 15;
#pragma unroll
    for (int i = 0; i < 4; ++i)
#pragma unroll
        for (int j = 0; j < 4; ++j)
#pragma unroll
            for (int r = 0; r < 4; ++r) {
                int grow = row0 + wm + i * 16 + cr + r;
                int gcol = col0 + wn + j * 16 + cc;
                store_c(&C[(long long)grow * ldc + gcol], acc[i][j][r]);
            }
}

// ---------- softmax over rows of S (fp32, len 2048) -> P (bf16) ----------
__global__ __launch_bounds__(256) void softmax_rows(
    const float* __restrict__ S, u16* __restrict__ P, float scale)
{
    const long long row = blockIdx.x;
    const float* s = S + row * 2048;
    u16* p = P + row * 2048;
    const int t = threadIdx.x;
    const int lane = t & 63, w = t >> 6;

    float v[8];
    float m = -1e30f;
#pragma unroll
    for (int i = 0; i < 8; ++i) {
        v[i] = s[t + i * 256] * scale;
        m = fmaxf(m, v[i]);
    }
#pragma unroll
    for (int off = 32; off > 0; off >>= 1) m = fmaxf(m, __shfl_xor(m, off, 64));
    __shared__ float sm[4], ss[4];
    if (lane == 0) sm[w] = m;
    __syncthreads();
    m = fmaxf(fmaxf(sm[0], sm[1]), fmaxf(sm[2], sm[3]));

    float sum = 0.f;
#pragma unroll
    for (int i = 0; i < 8; ++i) {
        v[i] = __expf(v[i] - m);
        sum += v[i];
    }
#pragma unroll
    for (int off = 32; off > 0; off >>= 1) sum += __shfl_xor(sum, off, 64);
    if (lane == 0) ss[w] = sum;
    __syncthreads();
    const float inv = 1.0f / (ss[0] + ss[1] + ss[2] + ss[3]);
#pragma unroll
    for (int i = 0; i < 8; ++i) p[t + i * 256] = f32_to_bf16(v[i] * inv);
}

// ---------- transpose V slice of qkv -> VT[b][d][s] ----------
__global__ void transpose_v(const u16* __restrict__ qkv, u16* __restrict__ VT)
{
    __shared__ u16 tile[32][33];
    const int b  = blockIdx.z;
    const int d0 = blockIdx.x * 32;
    const int s0 = blockIdx.y * 32;
    const int tx = threadIdx.x, ty = threadIdx.y;
#pragma unroll
    for (int i = 0; i < 4; ++i) {
        int s = s0 + ty + i * 8;
        tile[ty + i * 8][tx] =
            qkv[((long long)(b * 2048 + s)) * 3072 + 2048 + d0 + tx];
    }
    __syncthreads();
#pragma unroll
    for (int i = 0; i < 4; ++i) {
        int d = d0 + ty + i * 8;
        VT[((long long)(b * 1024 + d)) * 2048 + s0 + tx] = tile[tx][ty + i * 8];
    }
}

// ---------- launch ----------
extern "C" void kernel_launch(void* const* d_in, const int* in_sizes, int n_in,
                              void* d_out, int out_size, void* d_ws, size_t ws_size,
                              hipStream_t stream) {
    const float* x = (const float*)d_in[0];   // [4,2048,1024]
    const float* W = (const float*)d_in[1];   // [3072,1024]
    float* out = (float*)d_out;               // [4,2048,1024]

    char* ws = (char*)d_ws;
    // layout (bytes): Xb 16M | Wb 6M | QKV 50.3M | VT 16.8M | P 33.6M | S
    u16*   Xb  = (u16*)(ws);
    u16*   Wb  = (u16*)(ws + 16777216LL);
    u16*   QKV = (u16*)(ws + 23068672LL);
    u16*   VT  = (u16*)(ws + 73400320LL);
    u16*   P   = (u16*)(ws + 90177536LL);
    float* S   = (float*)(ws + 123731968LL);

    // batched S needs 4*2048*2048*4 = 67108864 B on top of 123731968
    const bool batched = (ws_size >= 123731968ULL + 67108864ULL);

    // 1) casts
    cast_f32_bf16_x4<<<8192, 256, 0, stream>>>(x, Xb, 8192 * 1024 / 4);
    cast_f32_bf16_x4<<<3072, 256, 0, stream>>>(W, Wb, 3072 * 1024 / 4);

    // 2) QKV = X * W^T   [8192,3072] bf16
    gemm_bt<u16><<<dim3(24, 64, 1), 256, 0, stream>>>(
        Xb, Wb, QKV, 8192, 3072, 1024, 1024, 1024, 3072, 0, 0, 0);

    // 3) V transpose (all batches)
    transpose_v<<<dim3(32, 64, 4), dim3(32, 8), 0, stream>>>(QKV, VT);

    // 4) S = Q K^T (fp32), softmax -> P (bf16)
    if (batched) {
        gemm_bt<float><<<dim3(16, 16, 4), 256, 0, stream>>>(
            QKV, QKV + 1024, S, 2048, 2048, 1024, 3072, 3072, 2048,
            2048LL * 3072, 2048LL * 3072, 2048LL * 2048);
        softmax_rows<<<8192, 256, 0, stream>>>(S, P, 0.03125f);
    } else {
        for (int b = 0; b < 4; ++b) {
            const u16* Qb = QKV + (long long)b * 2048 * 3072;
            gemm_bt<float><<<dim3(16, 16, 1), 256, 0, stream>>>(
                Qb, Qb + 1024, S, 2048, 2048, 1024, 3072, 3072, 2048, 0, 0, 0);
            softmax_rows<<<2048, 256, 0, stream>>>(
                S, P + (long long)b * 2048 * 2048, 0.03125f);
        }
    }

    // 5) Y = P * V  (via VT as Bt), batched over z
    gemm_bt<float><<<dim3(8, 16, 4), 256, 0, stream>>>(
        P, VT, out, 2048, 1024, 2048, 2048, 2048, 1024,
        2048LL * 2048, 1024LL * 2048, 2048LL * 1024);
}

// Round 4
// 271.117 us; speedup vs baseline: 1.2020x; 1.0461x over previous
//
#include <hip/hip_runtime.h>
#include <hip/hip_bf16.h>

// ---------- types ----------
typedef __attribute__((ext_vector_type(8))) short short8;    // 8 x bf16 (4 VGPRs)
typedef __attribute__((ext_vector_type(16))) float f32x16;   // 32x32 MFMA accumulator

typedef unsigned short u16;

__device__ __forceinline__ u16 f32_to_bf16(float f) {
    unsigned int u = __float_as_uint(f);
    u += 0x7fffu + ((u >> 16) & 1u);   // round-to-nearest-even
    return (u16)(u >> 16);
}
__device__ __forceinline__ float bf16_to_f32(u16 h) {
    return __uint_as_float(((unsigned int)h) << 16);
}

// async global->LDS, 16B per lane; LDS dest = wave-uniform base + lane*16
__device__ __forceinline__ void gload16(const u16* g, u16* lds_base) {
    __builtin_amdgcn_global_load_lds(
        (const __attribute__((address_space(1))) void*)g,
        (__attribute__((address_space(3))) void*)lds_base, 16, 0, 0);
}

// ---------- cast fp32 -> bf16, 4 elems/thread ----------
__global__ void cast_f32_bf16_x4(const float* __restrict__ in,
                                 u16* __restrict__ out, int n4) {
    int i = blockIdx.x * blockDim.x + threadIdx.x;
    if (i >= n4) return;
    float4 v = ((const float4*)in)[i];
    ushort4 o;
    o.x = f32_to_bf16(v.x); o.y = f32_to_bf16(v.y);
    o.z = f32_to_bf16(v.z); o.w = f32_to_bf16(v.w);
    ((ushort4*)out)[i] = o;
}

// ---------- output store helpers ----------
__device__ __forceinline__ void store_c(float* p, float v) { *p = v; }
__device__ __forceinline__ void store_c(u16* p, float v)   { *p = f32_to_bf16(v); }

// ---------- GEMM: C[M,N] = A[M,K] * Bt[N,K]^T  (both row-major, contiguous K) ----
// 128x128 block tile, BK=64, 256 threads (4 waves 2x2), each wave 64x64 via 2x2
// of v_mfma_f32_32x32x16_bf16. Staging via global_load_lds width=16 (m97
// structure). LDS unpadded (required by global_load_lds lane mapping); bank
// conflicts broken by XOR chunk swizzle: row r, 16B chunk slot p holds global
// chunk p ^ (r&7). Fragment reads are exactly one 16B chunk -> swizzle is free.

template <typename OutT>
__global__ __launch_bounds__(256) void gemm_bt(
    const u16* __restrict__ Abase, const u16* __restrict__ Bbase,
    OutT* __restrict__ Cbase, int M, int N, int K,
    int lda, int ldb, int ldc,
    long long sAb, long long sBb, long long sCb)
{
    const u16* A  = Abase + (long long)blockIdx.z * sAb;
    const u16* Bt = Bbase + (long long)blockIdx.z * sBb;
    OutT*      C  = Cbase + (long long)blockIdx.z * sCb;

    __shared__ u16 sA[128 * 64];
    __shared__ u16 sB[128 * 64];

    const int t    = threadIdx.x;
    const int lane = t & 63;
    const int wave = t >> 6;
    const int wm = (wave >> 1) * 64;
    const int wn = (wave & 1) * 64;
    const int la = lane & 31;            // fragment row (A) / col (B) within 32
    const int row0 = blockIdx.y * 128;
    const int col0 = blockIdx.x * 128;

    f32x16 acc[2][2];
#pragma unroll
    for (int i = 0; i < 2; ++i)
#pragma unroll
        for (int j = 0; j < 2; ++j)
            acc[i][j] = (f32x16)(0.f);

    // Staging: per K-tile each matrix is 128 rows x 64 bf16 (8 chunks of 16B).
    // One wave-issue covers 8 rows (64 lanes x 16B). 4 issues/wave/matrix.
    // lane -> row = base + lane/8, slot = lane&7; global chunk = slot ^ (r&7).
    const int srow = lane >> 3;                    // 0..7 within 8-row group
    const int gc   = (lane & 7) ^ srow;            // swizzled global chunk
    for (int k0 = 0; k0 < K; k0 += 64) {
        __syncthreads();
#pragma unroll
        for (int c = 0; c < 4; ++c) {
            const int rb = c * 32 + wave * 8;      // wave-uniform row base
            const int r  = rb + srow;
            gload16(A  + (long long)(row0 + r) * lda + k0 + gc * 8, &sA[rb * 64]);
            gload16(Bt + (long long)(col0 + r) * ldb + k0 + gc * 8, &sB[rb * 64]);
        }
        __syncthreads();   // compiler emits s_waitcnt vmcnt(0) before s_barrier

        // A-frag 32x32x16: row = lane&31, k = (lane>>5)*8 + j  (one 16B chunk)
#pragma unroll
        for (int kk = 0; kk < 64; kk += 16) {
            const int cb = (kk >> 3) + (lane >> 5);   // chunk index 0..7
            const int sl = (cb ^ (la & 7)) * 8;       // swizzled slot offset (elems)
            short8 af[2], bf[2];
#pragma unroll
            for (int i = 0; i < 2; ++i) {
                af[i] = *(const short8*)(&sA[(wm + i * 32 + la) * 64 + sl]);
                bf[i] = *(const short8*)(&sB[(wn + i * 32 + la) * 64 + sl]);
            }
#pragma unroll
            for (int i = 0; i < 2; ++i)
#pragma unroll
                for (int j = 0; j < 2; ++j)
                    acc[i][j] = __builtin_amdgcn_mfma_f32_32x32x16_bf16(
                        af[i], bf[j], acc[i][j], 0, 0, 0);
        }
    }

    // C/D layout (32x32): col = lane&31, row = (reg&3) + 8*(reg>>2) + 4*(lane>>5)
    const int rbase = 4 * (lane >> 5);
#pragma unroll
    for (int i = 0; i < 2; ++i)
#pragma unroll
        for (int j = 0; j < 2; ++j)
#pragma unroll
            for (int reg = 0; reg < 16; ++reg) {
                int grow = row0 + wm + i * 32 + rbase + (reg & 3) + 8 * (reg >> 2);
                int gcol = col0 + wn + j * 32 + la;
                store_c(&C[(long long)grow * ldc + gcol], acc[i][j][reg]);
            }
}

// ---------- softmax over rows of S (bf16, len 2048) -> P (bf16) ----------
// Each thread owns 8 contiguous elements (16B vector load/store).
__global__ __launch_bounds__(256) void softmax_rows(
    const u16* __restrict__ S, u16* __restrict__ P, float scale)
{
    const long long row = blockIdx.x;
    const u16* s = S + row * 2048;
    u16* p = P + row * 2048;
    const int t = threadIdx.x;
    const int lane = t & 63, w = t >> 6;

    short8 raw = *(const short8*)(s + t * 8);
    float v[8];
    float m = -1e30f;
#pragma unroll
    for (int i = 0; i < 8; ++i) {
        v[i] = bf16_to_f32((u16)raw[i]) * scale;
        m = fmaxf(m, v[i]);
    }
#pragma unroll
    for (int off = 32; off > 0; off >>= 1) m = fmaxf(m, __shfl_xor(m, off, 64));
    __shared__ float sm[4], ss[4];
    if (lane == 0) sm[w] = m;
    __syncthreads();
    m = fmaxf(fmaxf(sm[0], sm[1]), fmaxf(sm[2], sm[3]));

    float sum = 0.f;
#pragma unroll
    for (int i = 0; i < 8; ++i) {
        v[i] = __expf(v[i] - m);
        sum += v[i];
    }
#pragma unroll
    for (int off = 32; off > 0; off >>= 1) sum += __shfl_xor(sum, off, 64);
    if (lane == 0) ss[w] = sum;
    __syncthreads();
    const float inv = 1.0f / (ss[0] + ss[1] + ss[2] + ss[3]);
    short8 o;
#pragma unroll
    for (int i = 0; i < 8; ++i) o[i] = (short)f32_to_bf16(v[i] * inv);
    *(short8*)(p + t * 8) = o;
}

// ---------- transpose V slice of qkv -> VT[b][d][s] ----------
__global__ void transpose_v(const u16* __restrict__ qkv, u16* __restrict__ VT)
{
    __shared__ u16 tile[32][33];
    const int b  = blockIdx.z;
    const int d0 = blockIdx.x * 32;
    const int s0 = blockIdx.y * 32;
    const int tx = threadIdx.x, ty = threadIdx.y;
#pragma unroll
    for (int i = 0; i < 4; ++i) {
        int s = s0 + ty + i * 8;
        tile[ty + i * 8][tx] =
            qkv[((long long)(b * 2048 + s)) * 3072 + 2048 + d0 + tx];
    }
    __syncthreads();
#pragma unroll
    for (int i = 0; i < 4; ++i) {
        int d = d0 + ty + i * 8;
        VT[((long long)(b * 1024 + d)) * 2048 + s0 + tx] = tile[tx][ty + i * 8];
    }
}

// ---------- launch ----------
extern "C" void kernel_launch(void* const* d_in, const int* in_sizes, int n_in,
                              void* d_out, int out_size, void* d_ws, size_t ws_size,
                              hipStream_t stream) {
    const float* x = (const float*)d_in[0];   // [4,2048,1024]
    const float* W = (const float*)d_in[1];   // [3072,1024]
    float* out = (float*)d_out;               // [4,2048,1024]

    char* ws = (char*)d_ws;
    // layout (bytes): Xb 16M | Wb 6M | QKV 50.3M | VT 16.8M | P 33.6M | S(bf16) 33.6M
    u16*   Xb  = (u16*)(ws);
    u16*   Wb  = (u16*)(ws + 16777216LL);
    u16*   QKV = (u16*)(ws + 23068672LL);
    u16*   VT  = (u16*)(ws + 73400320LL);
    u16*   P   = (u16*)(ws + 90177536LL);
    u16*   S   = (u16*)(ws + 123731968LL);

    // batched S needs 4*2048*2048*2 = 33554432 B on top of 123731968
    const bool batched = (ws_size >= 123731968ULL + 33554432ULL);

    // 1) casts
    cast_f32_bf16_x4<<<8192, 256, 0, stream>>>(x, Xb, 8192 * 1024 / 4);
    cast_f32_bf16_x4<<<3072, 256, 0, stream>>>(W, Wb, 3072 * 1024 / 4);

    // 2) QKV = X * W^T   [8192,3072] bf16
    gemm_bt<u16><<<dim3(24, 64, 1), 256, 0, stream>>>(
        Xb, Wb, QKV, 8192, 3072, 1024, 1024, 1024, 3072, 0, 0, 0);

    // 3) V transpose (all batches)
    transpose_v<<<dim3(32, 64, 4), dim3(32, 8), 0, stream>>>(QKV, VT);

    // 4) S = Q K^T (bf16), softmax -> P (bf16)
    if (batched) {
        gemm_bt<u16><<<dim3(16, 16, 4), 256, 0, stream>>>(
            QKV, QKV + 1024, S, 2048, 2048, 1024, 3072, 3072, 2048,
            2048LL * 3072, 2048LL * 3072, 2048LL * 2048);
        softmax_rows<<<8192, 256, 0, stream>>>(S, P, 0.03125f);
    } else {
        for (int b = 0; b < 4; ++b) {
            const u16* Qb = QKV + (long long)b * 2048 * 3072;
            gemm_bt<u16><<<dim3(16, 16, 1), 256, 0, stream>>>(
                Qb, Qb + 1024, S, 2048, 2048, 1024, 3072, 3072, 2048, 0, 0, 0);
            softmax_rows<<<2048, 256, 0, stream>>>(
                S, P + (long long)b * 2048 * 2048, 0.03125f);
        }
    }

    // 5) Y = P * V  (via VT as Bt), batched over z
    gemm_bt<float><<<dim3(8, 16, 4), 256, 0, stream>>>(
        P, VT, out, 2048, 1024, 2048, 2048, 2048, 1024,
        2048LL * 2048, 1024LL * 2048, 2048LL * 1024);
}